// Round 19
// baseline (111.640 us; speedup 1.0000x reference)
//
#include <hip/hip_runtime.h>
#include <cmath>

#define C    128   // in/out channels
#define PAD  64    // padded CSR row stride (max supported in-degree)
#define NXCD 8     // XCDs on MI355X

typedef __bf16 bf16x8 __attribute__((ext_vector_type(8)));
typedef float  f32x4  __attribute__((ext_vector_type(4)));
typedef unsigned short u16x8 __attribute__((ext_vector_type(8)));

// fp32 -> bf16 bits, round-to-nearest-even
static __device__ __forceinline__ unsigned short f2b(float f) {
    unsigned int u = __builtin_bit_cast(unsigned int, f);
    u += 0x7FFFu + ((u >> 16) & 1u);
    return (unsigned short)(u >> 16);
}
// bf16 bits -> fp32
static __device__ __forceinline__ float b2f(unsigned short u) {
    return __builtin_bit_cast(float, (unsigned int)u << 16);
}

// ---------------------------------------------------------------------------
// Init, role by block range:
//  [0, ZB)   : zero counts (int4 stores)
//  [ZB,+16)  : pack A = [Wl ; Wr] (M=256 feats x K=128) into MFMA A-fragment
//              order: frag f = kt*16 + mt, lane l, elem j:
//                k = kt*32 + (l>>4)*8 + j, m = mt*16 + (l&15),
//                val = m<128 ? Wl[m][k] : Wr[m-128][k].
// ---------------------------------------------------------------------------
__global__ __launch_bounds__(256)
void sage_init(const float* __restrict__ Wl, const float* __restrict__ Wr,
               int4* __restrict__ counts4, unsigned short* __restrict__ wp,
               int n4, int ZB) {
    int bid = blockIdx.x;
    int t = threadIdx.x;
    if (bid < ZB) {
        int i = bid * 256 + t;
        if (i < n4) counts4[i] = make_int4(0, 0, 0, 0);
    } else {
        int s = (bid - ZB) * 256 + t;        // 0..4095
        int f = s >> 6, l = s & 63;
        int kt = f >> 4, mt = f & 15;
        int g = l >> 4;
        int m = mt * 16 + (l & 15);
        const float* src = (m < C) ? (Wl + (size_t)m * C)
                                   : (Wr + (size_t)(m - C) * C);
        u16x8 o;
#pragma unroll
        for (int j = 0; j < 8; ++j) o[j] = f2b(src[kt * 32 + g * 8 + j]);
        *(u16x8*)(wp + (size_t)s * 8) = o;
    }
}

// ---------------------------------------------------------------------------
// Fused fill + GEMM, 3:1 interleave in groups of 4 blocks:
//   pos = bid & 3, grp = bid >> 2
//   pos 0..2 -> fill block idx = grp*3 + pos   (FB total)
//   pos 3    -> GEMM block grp: FOUR 16-node tiles with W fragments
//               preloaded in registers once (W refetch 25 MB -> 6 MB,
//               block count 3125 -> 782, software-pipelined x loads).
//  fill : XCD-sliced padded-CSR (ushort ids), 8 edges/thread.
//  gemm : MFMA D = Wcat · x^T -> direct 8B bf16 stores, no LDS, no barriers;
//         waves 0,1 -> yl; waves 2,3 -> yr (+bias).
// ---------------------------------------------------------------------------
__global__ __launch_bounds__(256)
void sage_fill_gemm(const float* __restrict__ x,
                    const unsigned short* __restrict__ wp,
                    const float* __restrict__ bias,
                    const int* __restrict__ ei,
                    int* __restrict__ counts, unsigned short* __restrict__ csr,
                    unsigned short* __restrict__ yl,
                    unsigned short* __restrict__ yr,
                    int N, int E, int FB, int NT) {
    int bid = blockIdx.x;
    int t = threadIdx.x;
    int grp = bid >> 2;
    int pos = bid & 3;

    if (pos < 3) {
        // ---------------- fill role ----------------
        int idx = grp * 3 + pos;
        if (idx >= FB) return;
        int xcd = idx & (NXCD - 1);
        int chunk = idx >> 3;
        int span = (N + NXCD - 1) / NXCD;
        int lo = xcd * span;
        int hi = min(N, lo + span);
        int e0 = (chunk * 256 + t) * 8;
        if (e0 + 7 < E) {
            int4 d0 = *(const int4*)(ei + E + e0);
            int4 d1 = *(const int4*)(ei + E + e0 + 4);
            int4 s0 = *(const int4*)(ei + e0);
            int4 s1 = *(const int4*)(ei + e0 + 4);
            int dd[8] = {d0.x, d0.y, d0.z, d0.w, d1.x, d1.y, d1.z, d1.w};
            int ss[8] = {s0.x, s0.y, s0.z, s0.w, s1.x, s1.y, s1.z, s1.w};
#pragma unroll
            for (int j = 0; j < 8; ++j) {
                if (dd[j] >= lo && dd[j] < hi) {
                    int k = atomicAdd(&counts[dd[j]], 1);
                    if (k < PAD)
                        csr[(size_t)dd[j] * PAD + k] = (unsigned short)ss[j];
                }
            }
        } else {
            for (int e = e0; e < E; ++e) {
                int dst = ei[E + e];
                if (dst >= lo && dst < hi) {
                    int k = atomicAdd(&counts[dst], 1);
                    if (k < PAD)
                        csr[(size_t)dst * PAD + k] = (unsigned short)ei[e];
                }
            }
        }
        return;
    }

    // ---------------- GEMM role: 4 tiles, W in registers ----------------
    int w = t >> 6, l = t & 63;
    int g = l >> 4;
    const bf16x8* A = (const bf16x8*)wp;

    bf16x8 wf0[4], wf1[4], wf2[4], wf3[4];   // [kt] for feature-tile i=0..3
#pragma unroll
    for (int kt = 0; kt < 4; ++kt) {
        wf0[kt] = A[(size_t)(kt * 16 + w * 4 + 0) * 64 + l];
        wf1[kt] = A[(size_t)(kt * 16 + w * 4 + 1) * 64 + l];
        wf2[kt] = A[(size_t)(kt * 16 + w * 4 + 2) * 64 + l];
        wf3[kt] = A[(size_t)(kt * 16 + w * 4 + 3) * 64 + l];
    }
    float4 bv[4];
#pragma unroll
    for (int i = 0; i < 4; ++i) {
        int mt = w * 4 + i;
        bv[i] = (mt >= 8) ? *(const float4*)(bias + (mt - 8) * 16 + g * 4)
                          : make_float4(0.f, 0.f, 0.f, 0.f);
    }

#pragma unroll
    for (int tt = 0; tt < 4; ++tt) {
        int tile = grp * 4 + tt;
        if (tile >= NT) break;
        int node = tile * 16 + (l & 15);
        if (node >= N) node = N - 1;
        const float4* xv = (const float4*)(x + (size_t)node * C);

        f32x4 acc0 = {0.f,0.f,0.f,0.f}, acc1 = {0.f,0.f,0.f,0.f};
        f32x4 acc2 = {0.f,0.f,0.f,0.f}, acc3 = {0.f,0.f,0.f,0.f};

#pragma unroll
        for (int kt = 0; kt < 4; ++kt) {
            float4 xa = xv[kt * 8 + g * 2];
            float4 xc = xv[kt * 8 + g * 2 + 1];
            u16x8 ab;
            ab[0]=f2b(xa.x); ab[1]=f2b(xa.y); ab[2]=f2b(xa.z); ab[3]=f2b(xa.w);
            ab[4]=f2b(xc.x); ab[5]=f2b(xc.y); ab[6]=f2b(xc.z); ab[7]=f2b(xc.w);
            bf16x8 xf = __builtin_bit_cast(bf16x8, ab);
            acc0 = __builtin_amdgcn_mfma_f32_16x16x32_bf16(wf0[kt], xf, acc0, 0,0,0);
            acc1 = __builtin_amdgcn_mfma_f32_16x16x32_bf16(wf1[kt], xf, acc1, 0,0,0);
            acc2 = __builtin_amdgcn_mfma_f32_16x16x32_bf16(wf2[kt], xf, acc2, 0,0,0);
            acc3 = __builtin_amdgcn_mfma_f32_16x16x32_bf16(wf3[kt], xf, acc3, 0,0,0);
        }

        // D: col = node (l&15), row = feature (l>>4)*4 + reg  [verified m89]
        size_t rowoff = (size_t)node * C;
#pragma unroll
        for (int i = 0; i < 4; ++i) {
            f32x4 a = (i == 0) ? acc0 : (i == 1) ? acc1 : (i == 2) ? acc2 : acc3;
            int mt = w * 4 + i;
            ushort4 o;
            o.x = f2b(a[0] + bv[i].x);
            o.y = f2b(a[1] + bv[i].y);
            o.z = f2b(a[2] + bv[i].z);
            o.w = f2b(a[3] + bv[i].w);
            unsigned short* yp = (mt < 8) ? yl : yr;
            *(ushort4*)(yp + rowoff + (mt & 7) * 16 + g * 4) = o;
        }
    }
}

// ---------------------------------------------------------------------------
// Final: out = mean_gather(yl) + yr -> log_softmax. One wave per node, no
// LDS. Quarter-wave per neighbor row (16 lanes x 16 B = one 256 B bf16 row),
// 4-deep pipeline; cross-quarter shfl reduce; lanes 0-15 finish via shfl-lsm
// and float4 writes. CSR row base = node*PAD (ushort ids), len = min(cnt,PAD).
// ---------------------------------------------------------------------------
__global__ __launch_bounds__(256)
void sage_final(const unsigned short* __restrict__ yl,
                const unsigned short* __restrict__ yr,
                const int* __restrict__ counts,
                const unsigned short* __restrict__ csr,
                float* __restrict__ out, int N) {
    int wv = threadIdx.x >> 6;
    int node = blockIdx.x * 4 + wv;
    if (node >= N) return;
    int ln = threadIdx.x & 63;
    int q = ln >> 4;        // quarter: owns neighbor residues q (mod 4)
    int fl = ln & 15;       // 16B slot within the 256B row

    int deg = counts[node];
    deg = (deg > PAD) ? PAD : deg;
    int p0 = node * PAD;
    int p1 = p0 + deg;

    float a[8];
#pragma unroll
    for (int j = 0; j < 8; ++j) a[j] = 0.f;

    int p = p0 + q;
    for (; p + 12 < p1; p += 16) {
        int s0 = csr[p], s1 = csr[p + 4], s2 = csr[p + 8], s3 = csr[p + 12];
        u16x8 v0 = *(const u16x8*)(yl + (size_t)s0 * C + fl * 8);
        u16x8 v1 = *(const u16x8*)(yl + (size_t)s1 * C + fl * 8);
        u16x8 v2 = *(const u16x8*)(yl + (size_t)s2 * C + fl * 8);
        u16x8 v3 = *(const u16x8*)(yl + (size_t)s3 * C + fl * 8);
#pragma unroll
        for (int j = 0; j < 8; ++j)
            a[j] += (b2f(v0[j]) + b2f(v1[j])) + (b2f(v2[j]) + b2f(v3[j]));
    }
    for (; p + 4 < p1; p += 8) {
        int s0 = csr[p], s1 = csr[p + 4];
        u16x8 v0 = *(const u16x8*)(yl + (size_t)s0 * C + fl * 8);
        u16x8 v1 = *(const u16x8*)(yl + (size_t)s1 * C + fl * 8);
#pragma unroll
        for (int j = 0; j < 8; ++j) a[j] += b2f(v0[j]) + b2f(v1[j]);
    }
    if (p < p1) {
        int s0 = csr[p];
        u16x8 v0 = *(const u16x8*)(yl + (size_t)s0 * C + fl * 8);
#pragma unroll
        for (int j = 0; j < 8; ++j) a[j] += b2f(v0[j]);
    }

#pragma unroll
    for (int j = 0; j < 8; ++j) {
        a[j] += __shfl_xor(a[j], 16);
        a[j] += __shfl_xor(a[j], 32);
    }
    if (q != 0) return;

    float inv = 1.0f / fmaxf((float)deg, 1.0f);
    u16x8 yv = *(const u16x8*)(yr + (size_t)node * C + fl * 8);
#pragma unroll
    for (int j = 0; j < 8; ++j) a[j] = a[j] * inv + b2f(yv[j]);

    float m = a[0];
#pragma unroll
    for (int j = 1; j < 8; ++j) m = fmaxf(m, a[j]);
#pragma unroll
    for (int off = 1; off < 16; off <<= 1)
        m = fmaxf(m, __shfl_xor(m, off));
    float s = 0.f;
#pragma unroll
    for (int j = 0; j < 8; ++j) s += expf(a[j] - m);
#pragma unroll
    for (int off = 1; off < 16; off <<= 1)
        s += __shfl_xor(s, off);
    float ls = m + logf(s);

    float4 o0, o1;
    o0.x = a[0] - ls; o0.y = a[1] - ls; o0.z = a[2] - ls; o0.w = a[3] - ls;
    o1.x = a[4] - ls; o1.y = a[5] - ls; o1.z = a[6] - ls; o1.w = a[7] - ls;
    float4* op = (float4*)(out + (size_t)node * C + fl * 8);
    op[0] = o0;
    op[1] = o1;
}

extern "C" void kernel_launch(void* const* d_in, const int* in_sizes, int n_in,
                              void* d_out, int out_size, void* d_ws, size_t ws_size,
                              hipStream_t stream) {
    const float* x  = (const float*)d_in[0];
    const int*   ei = (const int*)d_in[1];
    const float* Wl = (const float*)d_in[2];
    const float* Wr = (const float*)d_in[3];
    const float* b  = (const float*)d_in[4];
    float* out = (float*)d_out;

    const int N = in_sizes[0] / C;   // 50000
    const int E = in_sizes[1] / 2;   // 600000

    // ws layout (all 16B-aligned): ~32.3 MB total
    int* counts = (int*)d_ws;                                  // N ints
    unsigned short* csr = (unsigned short*)(counts + ((N + 3) & ~3)); // N*PAD u16
    unsigned short* yl  = csr + (size_t)N * PAD;               // N*C bf16
    unsigned short* yr  = yl + (size_t)N * C;                  // N*C bf16
    unsigned short* wp  = yr + (size_t)N * C;                  // 256x128 bf16

    int n4 = (N + 3) / 4;
    const int ZB = (n4 + 255) / 256;                 // zero blocks
    const int NCH = (E + 2047) / 2048;               // edge chunks (8/thr)
    const int FB = NCH * NXCD;                       // fill blocks (2344)
    const int NT = (N + 15) / 16;                    // GEMM tiles (3125)
    const int GB = (NT + 3) / 4;                     // GEMM blocks (782)
    const int NGRP = (GB > (FB + 2) / 3) ? GB : (FB + 2) / 3;

    sage_init<<<ZB + 16, 256, 0, stream>>>(Wl, Wr, (int4*)counts, wp, n4, ZB);
    sage_fill_gemm<<<NGRP * 4, 256, 0, stream>>>(x, wp, b, ei, counts, csr,
                                                 yl, yr, N, E, FB, NT);
    sage_final<<<(N + 3) / 4, 256, 0, stream>>>(yl, yr, counts, csr, out, N);
}

// Round 20
// 86.840 us; speedup vs baseline: 1.2856x; 1.2856x over previous
//
#include <hip/hip_runtime.h>
#include <cmath>

#define C    128   // in/out channels
#define PAD  64    // padded CSR row stride (max supported in-degree)
#define NXCD 8     // XCDs on MI355X

typedef __bf16 bf16x8 __attribute__((ext_vector_type(8)));
typedef float  f32x4  __attribute__((ext_vector_type(4)));
typedef unsigned short u16x8 __attribute__((ext_vector_type(8)));

// fp32 -> bf16 bits, round-to-nearest-even
static __device__ __forceinline__ unsigned short f2b(float f) {
    unsigned int u = __builtin_bit_cast(unsigned int, f);
    u += 0x7FFFu + ((u >> 16) & 1u);
    return (unsigned short)(u >> 16);
}
// bf16 bits -> fp32
static __device__ __forceinline__ float b2f(unsigned short u) {
    return __builtin_bit_cast(float, (unsigned int)u << 16);
}

// ---------------------------------------------------------------------------
// Init, role by block range:
//  [0, ZB)   : zero counts (int4 stores)
//  [ZB,+16)  : pack A = [Wl ; Wr] (M=256 feats x K=128) into MFMA A-fragment
//              order: frag f = kt*16 + mt, lane l, elem j:
//                k = kt*32 + (l>>4)*8 + j, m = mt*16 + (l&15),
//                val = m<128 ? Wl[m][k] : Wr[m-128][k].
// ---------------------------------------------------------------------------
__global__ __launch_bounds__(256)
void sage_init(const float* __restrict__ Wl, const float* __restrict__ Wr,
               int4* __restrict__ counts4, unsigned short* __restrict__ wp,
               int n4, int ZB) {
    int bid = blockIdx.x;
    int t = threadIdx.x;
    if (bid < ZB) {
        int i = bid * 256 + t;
        if (i < n4) counts4[i] = make_int4(0, 0, 0, 0);
    } else {
        int s = (bid - ZB) * 256 + t;        // 0..4095
        int f = s >> 6, l = s & 63;
        int kt = f >> 4, mt = f & 15;
        int g = l >> 4;
        int m = mt * 16 + (l & 15);
        const float* src = (m < C) ? (Wl + (size_t)m * C)
                                   : (Wr + (size_t)(m - C) * C);
        u16x8 o;
#pragma unroll
        for (int j = 0; j < 8; ++j) o[j] = f2b(src[kt * 32 + g * 8 + j]);
        *(u16x8*)(wp + (size_t)s * 8) = o;
    }
}

// ---------------------------------------------------------------------------
// Fused fill + GEMM, 3:4 interleave in groups of 7 blocks (FB:NT = 2344:3125
// ≈ 3:4) so both roles exhaust simultaneously — no pure-role tail:
//   grp = bid/7, pos = bid%7; pos in {0,2,4} -> fill idx = grp*3 + pos/2,
//   pos in {1,3,5,6} -> GEMM tile = grp*4 + rank.
//  fill : XCD-sliced padded-CSR (ushort ids), 8 edges/thread (r18's best).
//  gemm : single-tile MFMA D = Wcat · x^T -> direct 8B bf16 stores, no LDS,
//         no barriers (52 VGPR keeps mixed-pool occupancy ~31%).
// ---------------------------------------------------------------------------
__global__ __launch_bounds__(256)
void sage_fill_gemm(const float* __restrict__ x,
                    const unsigned short* __restrict__ wp,
                    const float* __restrict__ bias,
                    const int* __restrict__ ei,
                    int* __restrict__ counts, unsigned short* __restrict__ csr,
                    unsigned short* __restrict__ yl,
                    unsigned short* __restrict__ yr,
                    int N, int E, int FB, int NT) {
    int bid = blockIdx.x;
    int t = threadIdx.x;
    int grp = bid / 7;
    int pos = bid % 7;
    bool is_fill = (pos == 0) | (pos == 2) | (pos == 4);

    if (is_fill) {
        // ---------------- fill role ----------------
        int idx = grp * 3 + (pos >> 1);
        if (idx >= FB) return;
        int xcd = idx & (NXCD - 1);
        int chunk = idx >> 3;
        int span = (N + NXCD - 1) / NXCD;
        int lo = xcd * span;
        int hi = min(N, lo + span);
        int e0 = (chunk * 256 + t) * 8;
        if (e0 + 7 < E) {
            int4 d0 = *(const int4*)(ei + E + e0);
            int4 d1 = *(const int4*)(ei + E + e0 + 4);
            int4 s0 = *(const int4*)(ei + e0);
            int4 s1 = *(const int4*)(ei + e0 + 4);
            int dd[8] = {d0.x, d0.y, d0.z, d0.w, d1.x, d1.y, d1.z, d1.w};
            int ss[8] = {s0.x, s0.y, s0.z, s0.w, s1.x, s1.y, s1.z, s1.w};
#pragma unroll
            for (int j = 0; j < 8; ++j) {
                if (dd[j] >= lo && dd[j] < hi) {
                    int k = atomicAdd(&counts[dd[j]], 1);
                    if (k < PAD)
                        csr[(size_t)dd[j] * PAD + k] = (unsigned short)ss[j];
                }
            }
        } else {
            for (int e = e0; e < E; ++e) {
                int dst = ei[E + e];
                if (dst >= lo && dst < hi) {
                    int k = atomicAdd(&counts[dst], 1);
                    if (k < PAD)
                        csr[(size_t)dst * PAD + k] = (unsigned short)ei[e];
                }
            }
        }
        return;
    }

    // ---------------- GEMM role ----------------
    int rank = (pos == 1) ? 0 : (pos == 3) ? 1 : (pos == 5) ? 2 : 3;
    int tile = grp * 4 + rank;
    if (tile >= NT) return;

    int w = t >> 6, l = t & 63;
    int g = l >> 4;

    int node = tile * 16 + (l & 15);
    if (node >= N) node = N - 1;
    const float4* xv = (const float4*)(x + (size_t)node * C);
    const bf16x8* A = (const bf16x8*)wp;

    f32x4 acc0 = {0.f,0.f,0.f,0.f}, acc1 = {0.f,0.f,0.f,0.f};
    f32x4 acc2 = {0.f,0.f,0.f,0.f}, acc3 = {0.f,0.f,0.f,0.f};

#pragma unroll
    for (int kt = 0; kt < 4; ++kt) {
        float4 xa = xv[kt * 8 + g * 2];
        float4 xc = xv[kt * 8 + g * 2 + 1];
        u16x8 ab;
        ab[0]=f2b(xa.x); ab[1]=f2b(xa.y); ab[2]=f2b(xa.z); ab[3]=f2b(xa.w);
        ab[4]=f2b(xc.x); ab[5]=f2b(xc.y); ab[6]=f2b(xc.z); ab[7]=f2b(xc.w);
        bf16x8 xf = __builtin_bit_cast(bf16x8, ab);
        int c = w * 4;
        bf16x8 a0 = A[(size_t)(kt * 16 + c + 0) * 64 + l];
        bf16x8 a1 = A[(size_t)(kt * 16 + c + 1) * 64 + l];
        bf16x8 a2 = A[(size_t)(kt * 16 + c + 2) * 64 + l];
        bf16x8 a3 = A[(size_t)(kt * 16 + c + 3) * 64 + l];
        acc0 = __builtin_amdgcn_mfma_f32_16x16x32_bf16(a0, xf, acc0, 0,0,0);
        acc1 = __builtin_amdgcn_mfma_f32_16x16x32_bf16(a1, xf, acc1, 0,0,0);
        acc2 = __builtin_amdgcn_mfma_f32_16x16x32_bf16(a2, xf, acc2, 0,0,0);
        acc3 = __builtin_amdgcn_mfma_f32_16x16x32_bf16(a3, xf, acc3, 0,0,0);
    }

    // D: col = node (l&15), row = feature (l>>4)*4 + reg  [verified m89]
    size_t rowoff = (size_t)node * C;
#pragma unroll
    for (int i = 0; i < 4; ++i) {
        f32x4 a = (i == 0) ? acc0 : (i == 1) ? acc1 : (i == 2) ? acc2 : acc3;
        int mt = w * 4 + i;
        float4 bv = (mt >= 8) ? *(const float4*)(bias + (mt - 8) * 16 + g * 4)
                              : make_float4(0.f, 0.f, 0.f, 0.f);
        ushort4 o;
        o.x = f2b(a[0] + bv.x);
        o.y = f2b(a[1] + bv.y);
        o.z = f2b(a[2] + bv.z);
        o.w = f2b(a[3] + bv.w);
        unsigned short* yp = (mt < 8) ? yl : yr;
        *(ushort4*)(yp + rowoff + (mt & 7) * 16 + g * 4) = o;
    }
}

// ---------------------------------------------------------------------------
// Final: out = mean_gather(yl) + yr -> log_softmax. One wave per node, no
// LDS. Quarter-wave per neighbor row (16 lanes x 16 B = one 256 B bf16 row),
// 4-deep pipeline; cross-quarter shfl reduce; lanes 0-15 finish via shfl-lsm
// and float4 writes. CSR row base = node*PAD (ushort ids), len = min(cnt,PAD).
// ---------------------------------------------------------------------------
__global__ __launch_bounds__(256)
void sage_final(const unsigned short* __restrict__ yl,
                const unsigned short* __restrict__ yr,
                const int* __restrict__ counts,
                const unsigned short* __restrict__ csr,
                float* __restrict__ out, int N) {
    int wv = threadIdx.x >> 6;
    int node = blockIdx.x * 4 + wv;
    if (node >= N) return;
    int ln = threadIdx.x & 63;
    int q = ln >> 4;        // quarter: owns neighbor residues q (mod 4)
    int fl = ln & 15;       // 16B slot within the 256B row

    int deg = counts[node];
    deg = (deg > PAD) ? PAD : deg;
    int p0 = node * PAD;
    int p1 = p0 + deg;

    float a[8];
#pragma unroll
    for (int j = 0; j < 8; ++j) a[j] = 0.f;

    int p = p0 + q;
    for (; p + 12 < p1; p += 16) {
        int s0 = csr[p], s1 = csr[p + 4], s2 = csr[p + 8], s3 = csr[p + 12];
        u16x8 v0 = *(const u16x8*)(yl + (size_t)s0 * C + fl * 8);
        u16x8 v1 = *(const u16x8*)(yl + (size_t)s1 * C + fl * 8);
        u16x8 v2 = *(const u16x8*)(yl + (size_t)s2 * C + fl * 8);
        u16x8 v3 = *(const u16x8*)(yl + (size_t)s3 * C + fl * 8);
#pragma unroll
        for (int j = 0; j < 8; ++j)
            a[j] += (b2f(v0[j]) + b2f(v1[j])) + (b2f(v2[j]) + b2f(v3[j]));
    }
    for (; p + 4 < p1; p += 8) {
        int s0 = csr[p], s1 = csr[p + 4];
        u16x8 v0 = *(const u16x8*)(yl + (size_t)s0 * C + fl * 8);
        u16x8 v1 = *(const u16x8*)(yl + (size_t)s1 * C + fl * 8);
#pragma unroll
        for (int j = 0; j < 8; ++j) a[j] += b2f(v0[j]) + b2f(v1[j]);
    }
    if (p < p1) {
        int s0 = csr[p];
        u16x8 v0 = *(const u16x8*)(yl + (size_t)s0 * C + fl * 8);
#pragma unroll
        for (int j = 0; j < 8; ++j) a[j] += b2f(v0[j]);
    }

#pragma unroll
    for (int j = 0; j < 8; ++j) {
        a[j] += __shfl_xor(a[j], 16);
        a[j] += __shfl_xor(a[j], 32);
    }
    if (q != 0) return;

    float inv = 1.0f / fmaxf((float)deg, 1.0f);
    u16x8 yv = *(const u16x8*)(yr + (size_t)node * C + fl * 8);
#pragma unroll
    for (int j = 0; j < 8; ++j) a[j] = a[j] * inv + b2f(yv[j]);

    float m = a[0];
#pragma unroll
    for (int j = 1; j < 8; ++j) m = fmaxf(m, a[j]);
#pragma unroll
    for (int off = 1; off < 16; off <<= 1)
        m = fmaxf(m, __shfl_xor(m, off));
    float s = 0.f;
#pragma unroll
    for (int j = 0; j < 8; ++j) s += expf(a[j] - m);
#pragma unroll
    for (int off = 1; off < 16; off <<= 1)
        s += __shfl_xor(s, off);
    float ls = m + logf(s);

    float4 o0, o1;
    o0.x = a[0] - ls; o0.y = a[1] - ls; o0.z = a[2] - ls; o0.w = a[3] - ls;
    o1.x = a[4] - ls; o1.y = a[5] - ls; o1.z = a[6] - ls; o1.w = a[7] - ls;
    float4* op = (float4*)(out + (size_t)node * C + fl * 8);
    op[0] = o0;
    op[1] = o1;
}

extern "C" void kernel_launch(void* const* d_in, const int* in_sizes, int n_in,
                              void* d_out, int out_size, void* d_ws, size_t ws_size,
                              hipStream_t stream) {
    const float* x  = (const float*)d_in[0];
    const int*   ei = (const int*)d_in[1];
    const float* Wl = (const float*)d_in[2];
    const float* Wr = (const float*)d_in[3];
    const float* b  = (const float*)d_in[4];
    float* out = (float*)d_out;

    const int N = in_sizes[0] / C;   // 50000
    const int E = in_sizes[1] / 2;   // 600000

    // ws layout (all 16B-aligned): ~32.3 MB total
    int* counts = (int*)d_ws;                                  // N ints
    unsigned short* csr = (unsigned short*)(counts + ((N + 3) & ~3)); // N*PAD u16
    unsigned short* yl  = csr + (size_t)N * PAD;               // N*C bf16
    unsigned short* yr  = yl + (size_t)N * C;                  // N*C bf16
    unsigned short* wp  = yr + (size_t)N * C;                  // 256x128 bf16

    int n4 = (N + 3) / 4;
    const int ZB = (n4 + 255) / 256;                 // zero blocks
    const int NCH = (E + 2047) / 2048;               // edge chunks (8/thr)
    const int FB = NCH * NXCD;                       // fill blocks (2344)
    const int NT = (N + 15) / 16;                    // GEMM tiles (3125)
    const int NG3 = (FB + 2) / 3;                    // groups needed for fill
    const int NG4 = (NT + 3) / 4;                    // groups needed for gemm
    const int NGRP = (NG3 > NG4) ? NG3 : NG4;        // 782

    sage_init<<<ZB + 16, 256, 0, stream>>>(Wl, Wr, (int4*)counts, wp, n4, ZB);
    sage_fill_gemm<<<NGRP * 7, 256, 0, stream>>>(x, wp, b, ei, counts, csr,
                                                 yl, yr, N, E, FB, NT);
    sage_final<<<(N + 3) / 4, 256, 0, stream>>>(yl, yr, counts, csr, out, N);
}

// Round 21
// 85.201 us; speedup vs baseline: 1.3103x; 1.0192x over previous
//
#include <hip/hip_runtime.h>
#include <cmath>

#define C    128   // in/out channels
#define PAD  64    // padded CSR row stride (max supported in-degree)

typedef __bf16 bf16x8 __attribute__((ext_vector_type(8)));
typedef float  f32x4  __attribute__((ext_vector_type(4)));
typedef unsigned short u16x8 __attribute__((ext_vector_type(8)));

// fp32 -> bf16 bits, round-to-nearest-even
static __device__ __forceinline__ unsigned short f2b(float f) {
    unsigned int u = __builtin_bit_cast(unsigned int, f);
    u += 0x7FFFu + ((u >> 16) & 1u);
    return (unsigned short)(u >> 16);
}
// bf16 bits -> fp32
static __device__ __forceinline__ float b2f(unsigned short u) {
    return __builtin_bit_cast(float, (unsigned int)u << 16);
}

// ---------------------------------------------------------------------------
// Init, role by block range:
//  [0, ZB)   : zero counts (int4 stores)
//  [ZB,+16)  : pack A = [Wl ; Wr] (M=256 feats x K=128) into MFMA A-fragment
//              order: frag f = kt*16 + mt, lane l, elem j:
//                k = kt*32 + (l>>4)*8 + j, m = mt*16 + (l&15),
//                val = m<128 ? Wl[m][k] : Wr[m-128][k].
// ---------------------------------------------------------------------------
__global__ __launch_bounds__(256)
void sage_init(const float* __restrict__ Wl, const float* __restrict__ Wr,
               int4* __restrict__ counts4, unsigned short* __restrict__ wp,
               int n4, int ZB) {
    int bid = blockIdx.x;
    int t = threadIdx.x;
    if (bid < ZB) {
        int i = bid * 256 + t;
        if (i < n4) counts4[i] = make_int4(0, 0, 0, 0);
    } else {
        int s = (bid - ZB) * 256 + t;        // 0..4095
        int f = s >> 6, l = s & 63;
        int kt = f >> 4, mt = f & 15;
        int g = l >> 4;
        int m = mt * 16 + (l & 15);
        const float* src = (m < C) ? (Wl + (size_t)m * C)
                                   : (Wr + (size_t)(m - C) * C);
        u16x8 o;
#pragma unroll
        for (int j = 0; j < 8; ++j) o[j] = f2b(src[kt * 32 + g * 8 + j]);
        *(u16x8*)(wp + (size_t)s * 8) = o;
    }
}

// ---------------------------------------------------------------------------
// Fused fill + GEMM, 1:10 interleave in groups of 11 blocks (FB:NT =
// 294:3125 ≈ 1:10.6): pos 0 -> fill, pos 1..10 -> GEMM.
//  fill : COMMIT-ALL padded-CSR (no XCD slicing — each edge read ONCE,
//         every lane commits; isolates whether slicing's 8x re-read tax
//         outweighed its L2-locality benefit). 8 edges/thread.
//  gemm : single-tile MFMA D = Wcat · x^T -> direct 8B bf16 stores, no LDS,
//         no barriers (52 VGPR keeps mixed-pool occupancy high).
// ---------------------------------------------------------------------------
__global__ __launch_bounds__(256)
void sage_fill_gemm(const float* __restrict__ x,
                    const unsigned short* __restrict__ wp,
                    const float* __restrict__ bias,
                    const int* __restrict__ ei,
                    int* __restrict__ counts, unsigned short* __restrict__ csr,
                    unsigned short* __restrict__ yl,
                    unsigned short* __restrict__ yr,
                    int N, int E, int FB, int NT) {
    int bid = blockIdx.x;
    int t = threadIdx.x;
    int grp = bid / 11;
    int pos = bid % 11;

    if (pos == 0) {
        // ---------------- fill role: commit-all, 8 edges/thread ----------------
        int idx = grp;
        if (idx >= FB) return;
        int e0 = (idx * 256 + t) * 8;
        if (e0 + 7 < E) {
            int4 d0 = *(const int4*)(ei + E + e0);
            int4 d1 = *(const int4*)(ei + E + e0 + 4);
            int4 s0 = *(const int4*)(ei + e0);
            int4 s1 = *(const int4*)(ei + e0 + 4);
            int dd[8] = {d0.x, d0.y, d0.z, d0.w, d1.x, d1.y, d1.z, d1.w};
            int ss[8] = {s0.x, s0.y, s0.z, s0.w, s1.x, s1.y, s1.z, s1.w};
#pragma unroll
            for (int j = 0; j < 8; ++j) {
                int k = atomicAdd(&counts[dd[j]], 1);
                if (k < PAD)
                    csr[(size_t)dd[j] * PAD + k] = (unsigned short)ss[j];
            }
        } else {
            for (int e = e0; e < E; ++e) {
                int dst = ei[E + e];
                int k = atomicAdd(&counts[dst], 1);
                if (k < PAD)
                    csr[(size_t)dst * PAD + k] = (unsigned short)ei[e];
            }
        }
        return;
    }

    // ---------------- GEMM role ----------------
    int tile = grp * 10 + (pos - 1);
    if (tile >= NT) return;

    int w = t >> 6, l = t & 63;
    int g = l >> 4;

    int node = tile * 16 + (l & 15);
    if (node >= N) node = N - 1;
    const float4* xv = (const float4*)(x + (size_t)node * C);
    const bf16x8* A = (const bf16x8*)wp;

    f32x4 acc0 = {0.f,0.f,0.f,0.f}, acc1 = {0.f,0.f,0.f,0.f};
    f32x4 acc2 = {0.f,0.f,0.f,0.f}, acc3 = {0.f,0.f,0.f,0.f};

#pragma unroll
    for (int kt = 0; kt < 4; ++kt) {
        float4 xa = xv[kt * 8 + g * 2];
        float4 xc = xv[kt * 8 + g * 2 + 1];
        u16x8 ab;
        ab[0]=f2b(xa.x); ab[1]=f2b(xa.y); ab[2]=f2b(xa.z); ab[3]=f2b(xa.w);
        ab[4]=f2b(xc.x); ab[5]=f2b(xc.y); ab[6]=f2b(xc.z); ab[7]=f2b(xc.w);
        bf16x8 xf = __builtin_bit_cast(bf16x8, ab);
        int c = w * 4;
        bf16x8 a0 = A[(size_t)(kt * 16 + c + 0) * 64 + l];
        bf16x8 a1 = A[(size_t)(kt * 16 + c + 1) * 64 + l];
        bf16x8 a2 = A[(size_t)(kt * 16 + c + 2) * 64 + l];
        bf16x8 a3 = A[(size_t)(kt * 16 + c + 3) * 64 + l];
        acc0 = __builtin_amdgcn_mfma_f32_16x16x32_bf16(a0, xf, acc0, 0,0,0);
        acc1 = __builtin_amdgcn_mfma_f32_16x16x32_bf16(a1, xf, acc1, 0,0,0);
        acc2 = __builtin_amdgcn_mfma_f32_16x16x32_bf16(a2, xf, acc2, 0,0,0);
        acc3 = __builtin_amdgcn_mfma_f32_16x16x32_bf16(a3, xf, acc3, 0,0,0);
    }

    // D: col = node (l&15), row = feature (l>>4)*4 + reg  [verified m89]
    size_t rowoff = (size_t)node * C;
#pragma unroll
    for (int i = 0; i < 4; ++i) {
        f32x4 a = (i == 0) ? acc0 : (i == 1) ? acc1 : (i == 2) ? acc2 : acc3;
        int mt = w * 4 + i;
        float4 bv = (mt >= 8) ? *(const float4*)(bias + (mt - 8) * 16 + g * 4)
                              : make_float4(0.f, 0.f, 0.f, 0.f);
        ushort4 o;
        o.x = f2b(a[0] + bv.x);
        o.y = f2b(a[1] + bv.y);
        o.z = f2b(a[2] + bv.z);
        o.w = f2b(a[3] + bv.w);
        unsigned short* yp = (mt < 8) ? yl : yr;
        *(ushort4*)(yp + rowoff + (mt & 7) * 16 + g * 4) = o;
    }
}

// ---------------------------------------------------------------------------
// Final: out = mean_gather(yl) + yr -> log_softmax. One wave per node, no
// LDS. Quarter-wave per neighbor row (16 lanes x 16 B = one 256 B bf16 row),
// 4-deep pipeline; cross-quarter shfl reduce; lanes 0-15 finish via shfl-lsm
// and float4 writes. CSR row base = node*PAD (ushort ids), len = min(cnt,PAD).
// ---------------------------------------------------------------------------
__global__ __launch_bounds__(256)
void sage_final(const unsigned short* __restrict__ yl,
                const unsigned short* __restrict__ yr,
                const int* __restrict__ counts,
                const unsigned short* __restrict__ csr,
                float* __restrict__ out, int N) {
    int wv = threadIdx.x >> 6;
    int node = blockIdx.x * 4 + wv;
    if (node >= N) return;
    int ln = threadIdx.x & 63;
    int q = ln >> 4;        // quarter: owns neighbor residues q (mod 4)
    int fl = ln & 15;       // 16B slot within the 256B row

    int deg = counts[node];
    deg = (deg > PAD) ? PAD : deg;
    int p0 = node * PAD;
    int p1 = p0 + deg;

    float a[8];
#pragma unroll
    for (int j = 0; j < 8; ++j) a[j] = 0.f;

    int p = p0 + q;
    for (; p + 12 < p1; p += 16) {
        int s0 = csr[p], s1 = csr[p + 4], s2 = csr[p + 8], s3 = csr[p + 12];
        u16x8 v0 = *(const u16x8*)(yl + (size_t)s0 * C + fl * 8);
        u16x8 v1 = *(const u16x8*)(yl + (size_t)s1 * C + fl * 8);
        u16x8 v2 = *(const u16x8*)(yl + (size_t)s2 * C + fl * 8);
        u16x8 v3 = *(const u16x8*)(yl + (size_t)s3 * C + fl * 8);
#pragma unroll
        for (int j = 0; j < 8; ++j)
            a[j] += (b2f(v0[j]) + b2f(v1[j])) + (b2f(v2[j]) + b2f(v3[j]));
    }
    for (; p + 4 < p1; p += 8) {
        int s0 = csr[p], s1 = csr[p + 4];
        u16x8 v0 = *(const u16x8*)(yl + (size_t)s0 * C + fl * 8);
        u16x8 v1 = *(const u16x8*)(yl + (size_t)s1 * C + fl * 8);
#pragma unroll
        for (int j = 0; j < 8; ++j) a[j] += b2f(v0[j]) + b2f(v1[j]);
    }
    if (p < p1) {
        int s0 = csr[p];
        u16x8 v0 = *(const u16x8*)(yl + (size_t)s0 * C + fl * 8);
#pragma unroll
        for (int j = 0; j < 8; ++j) a[j] += b2f(v0[j]);
    }

#pragma unroll
    for (int j = 0; j < 8; ++j) {
        a[j] += __shfl_xor(a[j], 16);
        a[j] += __shfl_xor(a[j], 32);
    }
    if (q != 0) return;

    float inv = 1.0f / fmaxf((float)deg, 1.0f);
    u16x8 yv = *(const u16x8*)(yr + (size_t)node * C + fl * 8);
#pragma unroll
    for (int j = 0; j < 8; ++j) a[j] = a[j] * inv + b2f(yv[j]);

    float m = a[0];
#pragma unroll
    for (int j = 1; j < 8; ++j) m = fmaxf(m, a[j]);
#pragma unroll
    for (int off = 1; off < 16; off <<= 1)
        m = fmaxf(m, __shfl_xor(m, off));
    float s = 0.f;
#pragma unroll
    for (int j = 0; j < 8; ++j) s += expf(a[j] - m);
#pragma unroll
    for (int off = 1; off < 16; off <<= 1)
        s += __shfl_xor(s, off);
    float ls = m + logf(s);

    float4 o0, o1;
    o0.x = a[0] - ls; o0.y = a[1] - ls; o0.z = a[2] - ls; o0.w = a[3] - ls;
    o1.x = a[4] - ls; o1.y = a[5] - ls; o1.z = a[6] - ls; o1.w = a[7] - ls;
    float4* op = (float4*)(out + (size_t)node * C + fl * 8);
    op[0] = o0;
    op[1] = o1;
}

extern "C" void kernel_launch(void* const* d_in, const int* in_sizes, int n_in,
                              void* d_out, int out_size, void* d_ws, size_t ws_size,
                              hipStream_t stream) {
    const float* x  = (const float*)d_in[0];
    const int*   ei = (const int*)d_in[1];
    const float* Wl = (const float*)d_in[2];
    const float* Wr = (const float*)d_in[3];
    const float* b  = (const float*)d_in[4];
    float* out = (float*)d_out;

    const int N = in_sizes[0] / C;   // 50000
    const int E = in_sizes[1] / 2;   // 600000

    // ws layout (all 16B-aligned): ~32.3 MB total
    int* counts = (int*)d_ws;                                  // N ints
    unsigned short* csr = (unsigned short*)(counts + ((N + 3) & ~3)); // N*PAD u16
    unsigned short* yl  = csr + (size_t)N * PAD;               // N*C bf16
    unsigned short* yr  = yl + (size_t)N * C;                  // N*C bf16
    unsigned short* wp  = yr + (size_t)N * C;                  // 256x128 bf16

    int n4 = (N + 3) / 4;
    const int ZB = (n4 + 255) / 256;                 // zero blocks
    const int FB = (E + 2047) / 2048;                // fill blocks (294)
    const int NT = (N + 15) / 16;                    // GEMM tiles (3125)
    const int NG1 = FB;                              // groups needed for fill
    const int NG10 = (NT + 9) / 10;                  // groups needed for gemm
    const int NGRP = (NG1 > NG10) ? NG1 : NG10;      // 313

    sage_init<<<ZB + 16, 256, 0, stream>>>(Wl, Wr, (int4*)counts, wp, n4, ZB);
    sage_fill_gemm<<<NGRP * 11, 256, 0, stream>>>(x, wp, b, ei, counts, csr,
                                                  yl, yr, N, E, FB, NT);
    sage_final<<<(N + 3) / 4, 256, 0, stream>>>(yl, yr, counts, csr, out, N);
}